// Round 16
// baseline (1518.039 us; speedup 1.0000x reference)
//
#include <hip/hip_runtime.h>

#define B_ 64
#define T_ 2048
#define F_ 8
#define H_ 128
#define RING_LD 68         // padded h1-ring row (dwords)
#define CHUNK 64
#define NCH (T_ / CHUNK)   // 32 chunks
#define GRING 16           // global h0 ring depth (chunks) per batch
#define H0_DW (CHUNK * 64) // dwords per published chunk (dense [64][64])
#define Z_LD 516           // padded z row (f32)

typedef _Float16 v2h   __attribute__((ext_vector_type(2)));
typedef _Float16 f16x8 __attribute__((ext_vector_type(8)));
typedef float    f32x4 __attribute__((ext_vector_type(4)));

__device__ __forceinline__ unsigned pk2h(float lo, float hi) {
    v2h p;
    p[0] = (_Float16)lo;
    p[1] = (_Float16)hi;
    return __builtin_bit_cast(unsigned, p);
}

#if __has_builtin(__builtin_amdgcn_fdot2)
__device__ __forceinline__ float fdot2a(unsigned a, unsigned b, float c) {
    return __builtin_amdgcn_fdot2(__builtin_bit_cast(v2h, a),
                                  __builtin_bit_cast(v2h, b), c, false);
}
#else
__device__ __forceinline__ float fdot2a(unsigned a, unsigned b, float c) {
    v2h av = __builtin_bit_cast(v2h, a);
    v2h bv = __builtin_bit_cast(v2h, b);
    c += (float)av[0] * (float)bv[0];
    c += (float)av[1] * (float)bv[1];
    return c;
}
#endif

__device__ __forceinline__ float sigm(float x) {
    return 1.0f / (1.0f + __expf(-x));
}
__device__ __forceinline__ float tanh_f(float x) {
    float e = __expf(2.0f * x);
    return 1.0f - 2.0f / (e + 1.0f);
}

__device__ __forceinline__ f32x4 mfma16(f16x8 a, f16x8 b, f32x4 c) {
    return __builtin_amdgcn_mfma_f32_16x16x32_f16(a, b, c, 0, 0, 0);
}

__device__ __forceinline__ f32x4 splat4(float v) {
    f32x4 r = {v, v, v, v};
    return r;
}

#if __has_builtin(__builtin_amdgcn_mov_dpp)
template <int CTRL>
__device__ __forceinline__ float qperm(float v) {
    int i = __builtin_bit_cast(int, v);
    i = __builtin_amdgcn_mov_dpp(i, CTRL, 0xF, 0xF, true);
    return __builtin_bit_cast(float, i);
}
__device__ __forceinline__ float lane_xor1(float v) { return qperm<0xB1>(v); }
__device__ __forceinline__ float lane_xor2(float v) { return qperm<0x4E>(v); }
#else
__device__ __forceinline__ float lane_xor1(float v) {
    int i = __builtin_amdgcn_ds_swizzle(__builtin_bit_cast(int, v), 0x041F);
    return __builtin_bit_cast(float, i);
}
__device__ __forceinline__ float lane_xor2(float v) {
    int i = __builtin_amdgcn_ds_swizzle(__builtin_bit_cast(int, v), 0x081F);
    return __builtin_bit_cast(float, i);
}
#endif

// ---------------------------------------------------------------------------
// r16 = r15 pipeline (verified, 1478us) with the serial-tick tail folded into
// MFMA C-in (both stages):
//   - bias folded into the z-GEMM C operand (splat; bias is tick-independent,
//     so adding it to every D row is exact),
//   - z (now z+bias) folded into the FIRST MFMA of the serial chain via C-in
//     (only element 0 of D is read; splat is safe),
//   => post-chain scalar tail shrinks to accvgpr-read + activations; the Z4
//      inits and 8 post-chain adds disappear; z LDS reads issue before the
//      h ds_reads (off critical path).
// Everything else byte-identical to r15 (handoff, GEMMs, OUT burst).
// ---------------------------------------------------------------------------
__global__ __launch_bounds__(512, 2)
void lstm2_pc6_kernel(const float* __restrict__ x,
                      const float* __restrict__ wih0,
                      const float* __restrict__ whh0,
                      const float* __restrict__ bih0,
                      const float* __restrict__ bhh0,
                      const float* __restrict__ wih1,
                      const float* __restrict__ whh1,
                      const float* __restrict__ bih1,
                      const float* __restrict__ bhh1,
                      const float* __restrict__ wlin,
                      const float* __restrict__ blin,
                      unsigned* __restrict__ h0g,
                      int* __restrict__ flags,
                      float* __restrict__ out)
{
    // consumer: h0c[64][68] | h1ring[64][68] | zih1[32][516]f32 | wlin[8][68]
    // producer: x_lds[8192] | ring[64][64] | z0[16][516]f32
    __shared__ __align__(16) unsigned arena[25760];   // ~100.6 KB
    __shared__ float blin_f[F_];

    const int tid = threadIdx.x;
    int* prog = flags;        // producer -> consumer: chunks published
    int* done = flags + 64;   // consumer -> producer: chunks consumed

    const int w   = tid >> 6;     // wave 0..7
    const int l   = tid & 63;     // lane
    const int n   = l & 15;       // fragment column / A-row index
    const int grp = l >> 4;       // k-slice group 0..3

    if (blockIdx.x < 64) {
        // =================== PRODUCER: layer 0 (MFMA tick) ===================
        const int b = blockIdx.x;
        unsigned* x_lds = arena;                     // 8192 dwords
        unsigned* ring  = arena + 8192;              // [64][64] h0 ring
        float*    z0    = (float*)(arena + 12288);   // [16][516] f32

        const float4* xp = (const float4*)(x + (size_t)b * T_ * F_);
        #pragma unroll
        for (int i = 0; i < 8; ++i) {
            int idx = tid + i * 512;
            float4 v = xp[idx];
            x_lds[idx * 2 + 0] = pk2h(v.x, v.y);
            x_lds[idx * 2 + 1] = pk2h(v.z, v.w);
        }

        // Whh0 as B-frags, pinned AGPR (exactly 128 dwords)
        f16x8 whh0f[4][4];
        #pragma unroll
        for (int j = 0; j < 4; ++j) {
            const int row = j * H_ + w * 16 + n;
            #pragma unroll
            for (int s = 0; s < 4; ++s) {
                const float* p0 = whh0 + (size_t)row * H_ + s * 32 + grp * 8;
                f16x8 f0;
                #pragma unroll
                for (int jj = 0; jj < 8; ++jj) f0[jj] = (_Float16)p0[jj];
                whh0f[j][s] = f0;
            }
        }
        #pragma unroll
        for (int j = 0; j < 4; ++j)
            #pragma unroll
            for (int s = 0; s < 4; ++s)
                asm("" : "+a"(whh0f[j][s]));

        // Wih0 B-frags (K=8 padded: only grp==0 lanes carry nonzero)
        f16x8 wih0f[4];
        #pragma unroll
        for (int j = 0; j < 4; ++j) {
            f16x8 f0 = {};
            if (grp == 0) {
                const float* p = wih0 + (size_t)(j * H_ + w * 16 + n) * F_;
                #pragma unroll
                for (int jj = 0; jj < 8; ++jj) f0[jj] = (_Float16)p[jj];
            }
            wih0f[j] = f0;
        }

        float bb0[4];
        #pragma unroll
        for (int j = 0; j < 4; ++j) {
            const int row = j * H_ + w * 16 + n;
            bb0[j] = bih0[row] + bhh0[row];
        }

        if (tid < 64) ring[63 * 64 + tid] = 0u;   // h0(-1) = 0
        __syncthreads();

        float c0 = 0.0f;

        for (int ch = 0; ch < NCH; ++ch) {
            for (int q = 0; q < 4; ++q) {
                // ---- zih0 GEMM for ticks [ch*64+q*16, +16); bias via C-in ----
                {
                    const int tg = ch * CHUNK + q * 16 + n;   // A row n = tick
                    f16x8 ax = (f16x8){};
                    if (grp == 0)
                        ax = __builtin_bit_cast(f16x8, *(const uint4*)&x_lds[tg * 4]);
                    f32x4 d0 = mfma16(ax, wih0f[0], splat4(bb0[0]));
                    f32x4 d1 = mfma16(ax, wih0f[1], splat4(bb0[1]));
                    f32x4 d2 = mfma16(ax, wih0f[2], splat4(bb0[2]));
                    f32x4 d3 = mfma16(ax, wih0f[3], splat4(bb0[3]));
                    #pragma unroll
                    for (int reg = 0; reg < 4; ++reg) {
                        const int zr = (grp * 4 + reg) * Z_LD + w * 16 + n;
                        z0[zr + 0 * H_] = d0[reg];
                        z0[zr + 1 * H_] = d1[reg];
                        z0[zr + 2 * H_] = d2[reg];
                        z0[zr + 3 * H_] = d3[reg];
                    }
                    // no barrier: wave w writes/reads only its own gate-cols
                }

                // ---- 16 serial ticks: z+bias enters via first MFMA C-in ----
                for (int tk = 0; tk < 16; ++tk) {
                    const int t = ch * CHUNK + q * 16 + tk;
                    const float* zz = &z0[tk * Z_LD + w * 16 + n];
                    float z0v = zz[0 * H_];
                    float z1v = zz[1 * H_];
                    float z2v = zz[2 * H_];
                    float z3v = zz[3 * H_];
                    const unsigned* hr = &ring[((t + 63) & 63) * 64];   // h0(t-1)
                    f32x4 a0, a1, a2, a3;
                    {
                        f16x8 ah = __builtin_bit_cast(f16x8, *(const uint4*)&hr[grp * 4]);
                        a0 = mfma16(ah, whh0f[0][0], splat4(z0v));
                        a1 = mfma16(ah, whh0f[1][0], splat4(z1v));
                        a2 = mfma16(ah, whh0f[2][0], splat4(z2v));
                        a3 = mfma16(ah, whh0f[3][0], splat4(z3v));
                    }
                    #pragma unroll
                    for (int s = 1; s < 4; ++s) {
                        f16x8 ah = __builtin_bit_cast(
                            f16x8, *(const uint4*)&hr[s * 16 + grp * 4]);
                        a0 = mfma16(ah, whh0f[0][s], a0);
                        a1 = mfma16(ah, whh0f[1][s], a1);
                        a2 = mfma16(ah, whh0f[2][s], a2);
                        a3 = mfma16(ah, whh0f[3][s], a3);
                    }
                    float gi = sigm(a0[0]);
                    float gf = sigm(a1[0]);
                    float gg = tanh_f(a2[0]);
                    float go = sigm(a3[0]);
                    c0 = gf * c0 + gi * gg;
                    float hh = go * tanh_f(c0);
                    if (l < 16)
                        ((_Float16*)&ring[(t & 63) * 64])[w * 16 + l] = (_Float16)hh;
                    __syncthreads();   // h0(t) visible
                }
            }

            // ---- publish chunk (r13-verified protocol) ----
            {
                if (ch >= GRING) {
                    while (__hip_atomic_load(&done[b], __ATOMIC_ACQUIRE,
                                             __HIP_MEMORY_SCOPE_AGENT) < ch - GRING + 1)
                        __builtin_amdgcn_s_sleep(8);
                    __syncthreads();
                }
                unsigned* dst = h0g + ((size_t)b * GRING + (ch & (GRING - 1))) * H0_DW;
                uint4 v0 = *(const uint4*)&ring[tid * 8];
                uint4 v1 = *(const uint4*)&ring[tid * 8 + 4];
                *(uint4*)&dst[tid * 8]     = v0;
                *(uint4*)&dst[tid * 8 + 4] = v1;
                __syncthreads();   // stores drained (vmcnt) before release
                if (tid == 0)
                    __hip_atomic_store(&prog[b], ch + 1, __ATOMIC_RELEASE,
                                       __HIP_MEMORY_SCOPE_AGENT);
            }
        }
    } else {
        // =================== CONSUMER: layer 1 + OUT ===================
        const int b = blockIdx.x - 64;
        unsigned* h0c    = arena;                    // [64][68] staged h0 (padded)
        unsigned* h1ring = arena + 4352;             // [64][68] h1 ring
        float*    zih1   = (float*)(arena + 8704);   // [32][516] f32
        unsigned* wlin_p = arena + 25216;            // [8][68]

        f16x8 wih1f[4][4], whh1f[4][4];
        #pragma unroll
        for (int j = 0; j < 4; ++j) {
            const int row = j * H_ + w * 16 + n;
            #pragma unroll
            for (int s = 0; s < 4; ++s) {
                const float* p1 = wih1 + (size_t)row * H_ + s * 32 + grp * 8;
                const float* p2 = whh1 + (size_t)row * H_ + s * 32 + grp * 8;
                f16x8 f1, f2;
                #pragma unroll
                for (int jj = 0; jj < 8; ++jj) {
                    f1[jj] = (_Float16)p1[jj];
                    f2[jj] = (_Float16)p2[jj];
                }
                wih1f[j][s] = f1;
                whh1f[j][s] = f2;
            }
        }
        #pragma unroll
        for (int j = 0; j < 4; ++j)
            #pragma unroll
            for (int s = 0; s < 4; ++s) {
                asm("" : "+a"(wih1f[j][s]));
                asm("" : "+a"(whh1f[j][s]));
            }

        float bb1[4];
        #pragma unroll
        for (int j = 0; j < 4; ++j) {
            const int row = j * H_ + w * 16 + n;
            bb1[j] = bih1[row] + bhh1[row];
        }
        {
            float2 v = ((const float2*)wlin)[tid];
            wlin_p[(tid >> 6) * RING_LD + (tid & 63)] = pk2h(v.x, v.y);
        }
        if (tid < F_) blin_f[tid] = blin[tid];
        if (tid < 64) h1ring[63 * RING_LD + tid] = 0u;   // h1(-1) = 0
        __syncthreads();

        float c1 = 0.0f;

        for (int c = 0; c < NCH; ++c) {
            while (__hip_atomic_load(&prog[b], __ATOMIC_ACQUIRE,
                                     __HIP_MEMORY_SCOPE_AGENT) < c + 1)
                __builtin_amdgcn_s_sleep(8);
            const unsigned* src = h0g + ((size_t)b * GRING + (c & (GRING - 1))) * H0_DW;
            {
                const int tick = tid >> 3;
                const int off  = (tid & 7) * 8;
                uint4 v0 = *(const uint4*)&src[tick * 64 + off];
                uint4 v1 = *(const uint4*)&src[tick * 64 + off + 4];
                *(uint4*)&h0c[tick * RING_LD + off]     = v0;
                *(uint4*)&h0c[tick * RING_LD + off + 4] = v1;
            }
            __syncthreads();   // staged (loads drained)
            if (tid == 0)
                __hip_atomic_store(&done[b], c + 1, __ATOMIC_RELAXED,
                                   __HIP_MEMORY_SCOPE_AGENT);

            for (int half = 0; half < 2; ++half) {
                // ---- batched GEMM: zih1 for 32 ticks; bias via C-in ----
                #pragma unroll
                for (int mt = 0; mt < 2; ++mt) {
                    f32x4 d0 = splat4(bb1[0]);
                    f32x4 d1 = splat4(bb1[1]);
                    f32x4 d2 = splat4(bb1[2]);
                    f32x4 d3 = splat4(bb1[3]);
                    const int trow = half * 32 + mt * 16 + n;
                    #pragma unroll
                    for (int s = 0; s < 4; ++s) {
                        f16x8 ah = __builtin_bit_cast(
                            f16x8, *(const uint4*)&h0c[trow * RING_LD + s * 16 + grp * 4]);
                        d0 = mfma16(ah, wih1f[0][s], d0);
                        d1 = mfma16(ah, wih1f[1][s], d1);
                        d2 = mfma16(ah, wih1f[2][s], d2);
                        d3 = mfma16(ah, wih1f[3][s], d3);
                    }
                    const int zr = mt * 16 + grp * 4;
                    #pragma unroll
                    for (int reg = 0; reg < 4; ++reg) {
                        zih1[(zr + reg) * Z_LD + 0 * H_ + w * 16 + n] = d0[reg];
                        zih1[(zr + reg) * Z_LD + 1 * H_ + w * 16 + n] = d1[reg];
                        zih1[(zr + reg) * Z_LD + 2 * H_ + w * 16 + n] = d2[reg];
                        zih1[(zr + reg) * Z_LD + 3 * H_ + w * 16 + n] = d3[reg];
                    }
                }
                // no barrier: zih1 cols of wave w written and read only by wave w

                // ---- 32 serial ticks: z+bias enters via first MFMA C-in ----
                for (int tk = 0; tk < 32; ++tk) {
                    const int t  = c * CHUNK + half * 32 + tk;
                    const float* zp = &zih1[tk * Z_LD + w * 16 + n];
                    float z0v = zp[0 * H_];
                    float z1v = zp[1 * H_];
                    float z2v = zp[2 * H_];
                    float z3v = zp[3 * H_];
                    const unsigned* h1r = &h1ring[((t + 63) & 63) * RING_LD];
                    f32x4 a0, a1, a2, a3;
                    {
                        f16x8 ah = __builtin_bit_cast(f16x8, *(const uint4*)&h1r[grp * 4]);
                        a0 = mfma16(ah, whh1f[0][0], splat4(z0v));
                        a1 = mfma16(ah, whh1f[1][0], splat4(z1v));
                        a2 = mfma16(ah, whh1f[2][0], splat4(z2v));
                        a3 = mfma16(ah, whh1f[3][0], splat4(z3v));
                    }
                    #pragma unroll
                    for (int s = 1; s < 4; ++s) {
                        f16x8 ah = __builtin_bit_cast(
                            f16x8, *(const uint4*)&h1r[s * 16 + grp * 4]);
                        a0 = mfma16(ah, whh1f[0][s], a0);
                        a1 = mfma16(ah, whh1f[1][s], a1);
                        a2 = mfma16(ah, whh1f[2][s], a2);
                        a3 = mfma16(ah, whh1f[3][s], a3);
                    }
                    float gi = sigm(a0[0]);
                    float gf = sigm(a1[0]);
                    float gg = tanh_f(a2[0]);
                    float go = sigm(a3[0]);
                    c1 = gf * c1 + gi * gg;
                    float hh = go * tanh_f(c1);
                    if (l < 16)
                        ((_Float16*)&h1ring[(t & 63) * RING_LD])[w * 16 + l] = (_Float16)hh;
                    __syncthreads();   // h1(t) visible
                }
            }

            // ---- OUT burst for this chunk (r13-verified pattern) ----
            {
                const int tick_i = tid >> 3;
                const int fo     = tid & 7;
                const unsigned* hp = &h1ring[tick_i * RING_LD];
                const unsigned* wv = &wlin_p[fo * RING_LD];
                float a = 0.0f;
                #pragma unroll
                for (int j = 0; j < 16; ++j) {
                    uint4 hv = *(const uint4*)&hp[j * 4];
                    uint4 wq = *(const uint4*)&wv[j * 4];
                    a = fdot2a(wq.x, hv.x, a);
                    a = fdot2a(wq.y, hv.y, a);
                    a = fdot2a(wq.z, hv.z, a);
                    a = fdot2a(wq.w, hv.w, a);
                }
                out[(size_t)b * T_ * F_ + (size_t)c * CHUNK * F_ + tid] = a + blin_f[fo];
                // drains at next chunk's staging barrier
            }
        }
    }
}

// ===================== Fallback (round-5 verified, 3162 us) =====================
__global__ __launch_bounds__(512, 2)
void lstm2_burst_kernel(const float* __restrict__ x,
                        const float* __restrict__ wih0,
                        const float* __restrict__ whh0,
                        const float* __restrict__ bih0,
                        const float* __restrict__ bhh0,
                        const float* __restrict__ wih1,
                        const float* __restrict__ whh1,
                        const float* __restrict__ bih1,
                        const float* __restrict__ bhh1,
                        const float* __restrict__ wlin,
                        const float* __restrict__ blin,
                        float* __restrict__ out)
{
    __shared__ __align__(16) unsigned x_lds[T_ * F_ / 2];
    __shared__ __align__(16) unsigned h0_p[2][H_ / 2];
    __shared__ __align__(16) unsigned h1_ring[64 * RING_LD];
    __shared__ __align__(16) unsigned wlin_p[F_ * RING_LD];
    __shared__ float blin_f[F_];

    const int tid   = threadIdx.x;
    const int b     = blockIdx.x;
    const int h_idx = tid >> 2;
    const int sub   = tid & 3;
    const int grow  = (0x3120 >> (sub * 4)) & 0xF;
    const int row   = grow * H_ + h_idx;

    const float4* xp = (const float4*)(x + (size_t)b * T_ * F_);
    #pragma unroll
    for (int i = 0; i < 8; ++i) {
        int idx = tid + i * 512;
        float4 v = xp[idx];
        x_lds[idx * 2 + 0] = pk2h(v.x, v.y);
        x_lds[idx * 2 + 1] = pk2h(v.z, v.w);
    }

    unsigned rwih0[4];
    {
        const float4* p = (const float4*)(wih0 + (size_t)row * F_);
        float4 v0 = p[0], v1 = p[1];
        rwih0[0] = pk2h(v0.x, v0.y); rwih0[1] = pk2h(v0.z, v0.w);
        rwih0[2] = pk2h(v1.x, v1.y); rwih0[3] = pk2h(v1.z, v1.w);
    }
    unsigned rwhh0[64], rwih1[64], rwhh1[64];
    {
        const float4* p = (const float4*)(whh0 + (size_t)row * H_);
        #pragma unroll
        for (int i = 0; i < 32; ++i) {
            float4 v = p[i];
            rwhh0[i * 2 + 0] = pk2h(v.x, v.y);
            rwhh0[i * 2 + 1] = pk2h(v.z, v.w);
        }
    }
    {
        const float4* p = (const float4*)(wih1 + (size_t)row * H_);
        #pragma unroll
        for (int i = 0; i < 32; ++i) {
            float4 v = p[i];
            rwih1[i * 2 + 0] = pk2h(v.x, v.y);
            rwih1[i * 2 + 1] = pk2h(v.z, v.w);
        }
    }
    {
        const float4* p = (const float4*)(whh1 + (size_t)row * H_);
        #pragma unroll
        for (int i = 0; i < 32; ++i) {
            float4 v = p[i];
            rwhh1[i * 2 + 0] = pk2h(v.x, v.y);
            rwhh1[i * 2 + 1] = pk2h(v.z, v.w);
        }
    }
    const float bias0 = bih0[row] + bhh0[row];
    const float bias1 = bih1[row] + bhh1[row];

    {
        int r = tid >> 6, c = tid & 63;
        float2 v = ((const float2*)wlin)[r * 64 + c];
        wlin_p[r * RING_LD + c] = pk2h(v.x, v.y);
    }
    if (tid < F_) blin_f[tid] = blin[tid];
    if (tid < H_ / 2) { h0_p[0][tid] = 0u; h0_p[1][tid] = 0u; }
    if (tid < H_ / 2) h1_ring[63 * RING_LD + tid] = 0u;
    __syncthreads();

    const bool is_g = (sub == 1);
    const bool lo2  = (sub < 2);
    float c0 = 0.0f, c1 = 0.0f;

    for (int t = 0; t < T_; ++t) {
        const int rp = (t + 1) & 1;
        const int wp = t & 1;
        {
            float aa = bias0, ab = 0.0f;
            uint4 xv = *(const uint4*)&x_lds[t * 4];
            aa = fdot2a(rwih0[0], xv.x, aa);
            ab = fdot2a(rwih0[1], xv.y, ab);
            aa = fdot2a(rwih0[2], xv.z, aa);
            ab = fdot2a(rwih0[3], xv.w, ab);
            const unsigned* hr = &h0_p[rp][0];
            #pragma unroll
            for (int j = 0; j < 16; ++j) {
                uint4 hv = *(const uint4*)&hr[j * 4];
                aa = fdot2a(rwhh0[j * 4 + 0], hv.x, aa);
                ab = fdot2a(rwhh0[j * 4 + 1], hv.y, ab);
                aa = fdot2a(rwhh0[j * 4 + 2], hv.z, aa);
                ab = fdot2a(rwhh0[j * 4 + 3], hv.w, ab);
            }
            float a = aa + ab;
            float xin = is_g ? 2.0f * a : a;
            float s   = sigm(xin);
            float act = is_g ? 2.0f * s - 1.0f : s;
            float s1  = lane_xor1(act);
            float p   = lo2 ? act * s1 : (sub == 2 ? act : s1) * c0;
            float cn  = p + lane_xor2(p);
            c0 = cn;
            float oval = (sub == 2) ? s1 : act;
            float h = oval * tanh_f(cn);
            if (sub == 2) ((_Float16*)&h0_p[wp][0])[h_idx] = (_Float16)h;
        }
        __syncthreads();
        {
            float aa = bias1, ab = 0.0f, ba = 0.0f, bb = 0.0f;
            const unsigned* h0r = &h0_p[wp][0];
            const unsigned* h1r = &h1_ring[((t + 63) & 63) * RING_LD];
            #pragma unroll
            for (int j = 0; j < 16; ++j) {
                uint4 hv0 = *(const uint4*)&h0r[j * 4];
                uint4 hv1 = *(const uint4*)&h1r[j * 4];
                aa = fdot2a(rwih1[j * 4 + 0], hv0.x, aa);
                ab = fdot2a(rwih1[j * 4 + 1], hv0.y, ab);
                aa = fdot2a(rwih1[j * 4 + 2], hv0.z, aa);
                ab = fdot2a(rwih1[j * 4 + 3], hv0.w, ab);
                ba = fdot2a(rwhh1[j * 4 + 0], hv1.x, ba);
                bb = fdot2a(rwhh1[j * 4 + 1], hv1.y, bb);
                ba = fdot2a(rwhh1[j * 4 + 2], hv1.z, ba);
                bb = fdot2a(rwhh1[j * 4 + 3], hv1.w, bb);
            }
            float a = (aa + ab) + (ba + bb);
            float xin = is_g ? 2.0f * a : a;
            float s   = sigm(xin);
            float act = is_g ? 2.0f * s - 1.0f : s;
            float s1  = lane_xor1(act);
            float p   = lo2 ? act * s1 : (sub == 2 ? act : s1) * c1;
            float cn  = p + lane_xor2(p);
            c1 = cn;
            float oval = (sub == 2) ? s1 : act;
            float h = oval * tanh_f(cn);
            if (sub == 2)
                ((_Float16*)&h1_ring[(t & 63) * RING_LD])[h_idx] = (_Float16)h;
        }
        __syncthreads();
        if ((t & 63) == 63) {
            const int tick_i = tid >> 3;
            const int fo     = tid & 7;
            const unsigned* hp = &h1_ring[tick_i * RING_LD];
            const unsigned* wv = &wlin_p[fo * RING_LD];
            float a = 0.0f;
            #pragma unroll
            for (int j = 0; j < 16; ++j) {
                uint4 hv = *(const uint4*)&hp[j * 4];
                uint4 wq = *(const uint4*)&wv[j * 4];
                a = fdot2a(wq.x, hv.x, a);
                a = fdot2a(wq.y, hv.y, a);
                a = fdot2a(wq.z, hv.z, a);
                a = fdot2a(wq.w, hv.w, a);
            }
            out[(size_t)b * T_ * F_ + (size_t)(t - 63) * F_ + tid] = a + blin_f[fo];
        }
    }
}

extern "C" void kernel_launch(void* const* d_in, const int* in_sizes, int n_in,
                              void* d_out, int out_size, void* d_ws, size_t ws_size,
                              hipStream_t stream) {
    const float* x    = (const float*)d_in[0];
    const float* wih0 = (const float*)d_in[1];
    const float* whh0 = (const float*)d_in[2];
    const float* bih0 = (const float*)d_in[3];
    const float* bhh0 = (const float*)d_in[4];
    const float* wih1 = (const float*)d_in[5];
    const float* whh1 = (const float*)d_in[6];
    const float* bih1 = (const float*)d_in[7];
    const float* bhh1 = (const float*)d_in[8];
    const float* wlin = (const float*)d_in[9];
    const float* blin = (const float*)d_in[10];
    float* out = (float*)d_out;

    const size_t h0_bytes = (size_t)B_ * GRING * H0_DW * sizeof(unsigned);  // 16 MB
    const size_t need = h0_bytes + 512;
    if (d_ws != nullptr && ws_size >= need) {
        unsigned* h0g = (unsigned*)d_ws;
        int* flags = (int*)((char*)d_ws + h0_bytes);   // prog[64], done[64]
        hipMemsetAsync(flags, 0, 512, stream);
        lstm2_pc6_kernel<<<dim3(128), dim3(512), 0, stream>>>(
            x, wih0, whh0, bih0, bhh0, wih1, whh1, bih1, bhh1, wlin, blin,
            h0g, flags, out);
    } else {
        lstm2_burst_kernel<<<dim3(B_), dim3(512), 0, stream>>>(
            x, wih0, whh0, bih0, bhh0, wih1, whh1, bih1, bhh1, wlin, blin, out);
    }
}

// Round 17
// 1479.472 us; speedup vs baseline: 1.0261x; 1.0261x over previous
//
#include <hip/hip_runtime.h>

#define B_ 64
#define T_ 2048
#define F_ 8
#define H_ 128
#define RING_LD 68         // padded h1-ring row (dwords)
#define CHUNK 64
#define NCH (T_ / CHUNK)   // 32 chunks
#define GRING 16           // global h0 ring depth (chunks) per batch
#define H0_DW (CHUNK * 64) // dwords per published chunk (dense [64][64])
#define Z_LD 516           // padded z row (f32)

typedef _Float16 v2h   __attribute__((ext_vector_type(2)));
typedef _Float16 f16x8 __attribute__((ext_vector_type(8)));
typedef float    f32x4 __attribute__((ext_vector_type(4)));

__device__ __forceinline__ unsigned pk2h(float lo, float hi) {
    v2h p;
    p[0] = (_Float16)lo;
    p[1] = (_Float16)hi;
    return __builtin_bit_cast(unsigned, p);
}

#if __has_builtin(__builtin_amdgcn_fdot2)
__device__ __forceinline__ float fdot2a(unsigned a, unsigned b, float c) {
    return __builtin_amdgcn_fdot2(__builtin_bit_cast(v2h, a),
                                  __builtin_bit_cast(v2h, b), c, false);
}
#else
__device__ __forceinline__ float fdot2a(unsigned a, unsigned b, float c) {
    v2h av = __builtin_bit_cast(v2h, a);
    v2h bv = __builtin_bit_cast(v2h, b);
    c += (float)av[0] * (float)bv[0];
    c += (float)av[1] * (float)bv[1];
    return c;
}
#endif

__device__ __forceinline__ float sigm(float x) {
    return 1.0f / (1.0f + __expf(-x));
}
__device__ __forceinline__ float tanh_f(float x) {
    float e = __expf(2.0f * x);
    return 1.0f - 2.0f / (e + 1.0f);
}

__device__ __forceinline__ f32x4 mfma16(f16x8 a, f16x8 b, f32x4 c) {
    return __builtin_amdgcn_mfma_f32_16x16x32_f16(a, b, c, 0, 0, 0);
}

#if __has_builtin(__builtin_amdgcn_mov_dpp)
template <int CTRL>
__device__ __forceinline__ float qperm(float v) {
    int i = __builtin_bit_cast(int, v);
    i = __builtin_amdgcn_mov_dpp(i, CTRL, 0xF, 0xF, true);
    return __builtin_bit_cast(float, i);
}
__device__ __forceinline__ float lane_xor1(float v) { return qperm<0xB1>(v); }
__device__ __forceinline__ float lane_xor2(float v) { return qperm<0x4E>(v); }
#else
__device__ __forceinline__ float lane_xor1(float v) {
    int i = __builtin_amdgcn_ds_swizzle(__builtin_bit_cast(int, v), 0x041F);
    return __builtin_bit_cast(float, i);
}
__device__ __forceinline__ float lane_xor2(float v) {
    int i = __builtin_amdgcn_ds_swizzle(__builtin_bit_cast(int, v), 0x081F);
    return __builtin_bit_cast(float, i);
}
#endif

// ---------------------------------------------------------------------------
// FINAL (= round-15 verified, 1478us; r16's C-in fold regressed 2.7% and is
// reverted). Producer-consumer layer pipeline across 128 CUs:
//   blocks 0..63  : L0 — zih0 = Wih0*x precomputed per 16-tick quarter as a
//     K=8-padded MFMA GEMM; Whh0 as 16 B-frags = 128 dw pinned "+a" (AGPR,
//     read natively by MFMA); serial tick = 4 ring reads + 4-deep MFMA chain
//     + z/bias add + per-lane activations + 1 barrier.
//   blocks 64..127: L1+OUT — h0 chunk staged to LDS, zih1 batched GEMM per
//     32 ticks, same 4-deep serial tick; OUT via per-chunk fdot2 burst.
// Handoff: 16-chunk global ring in d_ws (L3-resident), agent-scope
// acquire/release flags, all global ops per-chunk (r4 lesson).
// Session ledger: 3418 -> 1478us (2.31x). Exhausted-with-evidence: barrier
// merging (r10 -10%), register-class matching (r7/r8/r11 null), occupancy
// up/down (r1, r8 -2.4x), dual-batch ILP (r14 0%), per-tick global sync
// (r4 -3.6x), C-in tail fold (r16 -2.7%).
// ---------------------------------------------------------------------------
__global__ __launch_bounds__(512, 2)
void lstm2_pc5_kernel(const float* __restrict__ x,
                      const float* __restrict__ wih0,
                      const float* __restrict__ whh0,
                      const float* __restrict__ bih0,
                      const float* __restrict__ bhh0,
                      const float* __restrict__ wih1,
                      const float* __restrict__ whh1,
                      const float* __restrict__ bih1,
                      const float* __restrict__ bhh1,
                      const float* __restrict__ wlin,
                      const float* __restrict__ blin,
                      unsigned* __restrict__ h0g,
                      int* __restrict__ flags,
                      float* __restrict__ out)
{
    // consumer: h0c[64][68] | h1ring[64][68] | zih1[32][516]f32 | wlin[8][68]
    // producer: x_lds[8192] | ring[64][64] | z0[16][516]f32
    __shared__ __align__(16) unsigned arena[25760];   // ~100.6 KB
    __shared__ float blin_f[F_];

    const int tid = threadIdx.x;
    int* prog = flags;        // producer -> consumer: chunks published
    int* done = flags + 64;   // consumer -> producer: chunks consumed

    const int w   = tid >> 6;     // wave 0..7
    const int l   = tid & 63;     // lane
    const int n   = l & 15;       // fragment column / A-row index
    const int grp = l >> 4;       // k-slice group 0..3

    if (blockIdx.x < 64) {
        // =================== PRODUCER: layer 0 (MFMA tick) ===================
        const int b = blockIdx.x;
        unsigned* x_lds = arena;                     // 8192 dwords
        unsigned* ring  = arena + 8192;              // [64][64] h0 ring
        float*    z0    = (float*)(arena + 12288);   // [16][516] f32

        const float4* xp = (const float4*)(x + (size_t)b * T_ * F_);
        #pragma unroll
        for (int i = 0; i < 8; ++i) {
            int idx = tid + i * 512;
            float4 v = xp[idx];
            x_lds[idx * 2 + 0] = pk2h(v.x, v.y);
            x_lds[idx * 2 + 1] = pk2h(v.z, v.w);
        }

        // Whh0 as B-frags, pinned AGPR (exactly 128 dwords)
        // frag [j][s]: elem jj = Whh0[j*128 + w*16 + n][s*32 + grp*8 + jj]
        f16x8 whh0f[4][4];
        #pragma unroll
        for (int j = 0; j < 4; ++j) {
            const int row = j * H_ + w * 16 + n;
            #pragma unroll
            for (int s = 0; s < 4; ++s) {
                const float* p0 = whh0 + (size_t)row * H_ + s * 32 + grp * 8;
                f16x8 f0;
                #pragma unroll
                for (int jj = 0; jj < 8; ++jj) f0[jj] = (_Float16)p0[jj];
                whh0f[j][s] = f0;
            }
        }
        #pragma unroll
        for (int j = 0; j < 4; ++j)
            #pragma unroll
            for (int s = 0; s < 4; ++s)
                asm("" : "+a"(whh0f[j][s]));

        // Wih0 B-frags (K=8 padded: only grp==0 lanes carry nonzero)
        f16x8 wih0f[4];
        #pragma unroll
        for (int j = 0; j < 4; ++j) {
            f16x8 f0 = {};
            if (grp == 0) {
                const float* p = wih0 + (size_t)(j * H_ + w * 16 + n) * F_;
                #pragma unroll
                for (int jj = 0; jj < 8; ++jj) f0[jj] = (_Float16)p[jj];
            }
            wih0f[j] = f0;
        }

        float bb0[4];
        #pragma unroll
        for (int j = 0; j < 4; ++j) {
            const int row = j * H_ + w * 16 + n;
            bb0[j] = bih0[row] + bhh0[row];
        }

        if (tid < 64) ring[63 * 64 + tid] = 0u;   // h0(-1) = 0
        __syncthreads();

        float c0 = 0.0f;
        const f32x4 Z4 = {0.0f, 0.0f, 0.0f, 0.0f};

        for (int ch = 0; ch < NCH; ++ch) {
            for (int q = 0; q < 4; ++q) {
                // ---- zih0 GEMM for ticks [ch*64+q*16, +16) (4 MFMAs) ----
                {
                    const int tg = ch * CHUNK + q * 16 + n;   // A row n = tick
                    f16x8 ax = (f16x8){};
                    if (grp == 0)
                        ax = __builtin_bit_cast(f16x8, *(const uint4*)&x_lds[tg * 4]);
                    f32x4 d0 = mfma16(ax, wih0f[0], Z4);
                    f32x4 d1 = mfma16(ax, wih0f[1], Z4);
                    f32x4 d2 = mfma16(ax, wih0f[2], Z4);
                    f32x4 d3 = mfma16(ax, wih0f[3], Z4);
                    #pragma unroll
                    for (int reg = 0; reg < 4; ++reg) {
                        const int zr = (grp * 4 + reg) * Z_LD + w * 16 + n;
                        z0[zr + 0 * H_] = d0[reg];
                        z0[zr + 1 * H_] = d1[reg];
                        z0[zr + 2 * H_] = d2[reg];
                        z0[zr + 3 * H_] = d3[reg];
                    }
                    // no barrier: wave w writes/reads only its own gate-cols
                }

                // ---- 16 serial ticks (4-deep MFMA chain) ----
                for (int tk = 0; tk < 16; ++tk) {
                    const int t = ch * CHUNK + q * 16 + tk;
                    const unsigned* hr = &ring[((t + 63) & 63) * 64];   // h0(t-1)
                    f32x4 a0, a1, a2, a3;
                    {
                        f16x8 ah = __builtin_bit_cast(f16x8, *(const uint4*)&hr[grp * 4]);
                        a0 = mfma16(ah, whh0f[0][0], Z4);
                        a1 = mfma16(ah, whh0f[1][0], Z4);
                        a2 = mfma16(ah, whh0f[2][0], Z4);
                        a3 = mfma16(ah, whh0f[3][0], Z4);
                    }
                    #pragma unroll
                    for (int s = 1; s < 4; ++s) {
                        f16x8 ah = __builtin_bit_cast(
                            f16x8, *(const uint4*)&hr[s * 16 + grp * 4]);
                        a0 = mfma16(ah, whh0f[0][s], a0);
                        a1 = mfma16(ah, whh0f[1][s], a1);
                        a2 = mfma16(ah, whh0f[2][s], a2);
                        a3 = mfma16(ah, whh0f[3][s], a3);
                    }
                    const float* zz = &z0[tk * Z_LD + w * 16 + n];
                    float gi = sigm(a0[0] + zz[0 * H_] + bb0[0]);
                    float gf = sigm(a1[0] + zz[1 * H_] + bb0[1]);
                    float gg = tanh_f(a2[0] + zz[2 * H_] + bb0[2]);
                    float go = sigm(a3[0] + zz[3 * H_] + bb0[3]);
                    c0 = gf * c0 + gi * gg;
                    float hh = go * tanh_f(c0);
                    if (l < 16)
                        ((_Float16*)&ring[(t & 63) * 64])[w * 16 + l] = (_Float16)hh;
                    __syncthreads();   // h0(t) visible
                }
            }

            // ---- publish chunk (r13-verified protocol) ----
            {
                if (ch >= GRING) {
                    while (__hip_atomic_load(&done[b], __ATOMIC_ACQUIRE,
                                             __HIP_MEMORY_SCOPE_AGENT) < ch - GRING + 1)
                        __builtin_amdgcn_s_sleep(8);
                    __syncthreads();
                }
                unsigned* dst = h0g + ((size_t)b * GRING + (ch & (GRING - 1))) * H0_DW;
                uint4 v0 = *(const uint4*)&ring[tid * 8];
                uint4 v1 = *(const uint4*)&ring[tid * 8 + 4];
                *(uint4*)&dst[tid * 8]     = v0;
                *(uint4*)&dst[tid * 8 + 4] = v1;
                __syncthreads();   // stores drained (vmcnt) before release
                if (tid == 0)
                    __hip_atomic_store(&prog[b], ch + 1, __ATOMIC_RELEASE,
                                       __HIP_MEMORY_SCOPE_AGENT);
            }
        }
    } else {
        // =================== CONSUMER: layer 1 + OUT ===================
        const int b = blockIdx.x - 64;
        unsigned* h0c    = arena;                    // [64][68] staged h0 (padded)
        unsigned* h1ring = arena + 4352;             // [64][68] h1 ring
        float*    zih1   = (float*)(arena + 8704);   // [32][516] f32
        unsigned* wlin_p = arena + 25216;            // [8][68]

        f16x8 wih1f[4][4], whh1f[4][4];
        #pragma unroll
        for (int j = 0; j < 4; ++j) {
            const int row = j * H_ + w * 16 + n;
            #pragma unroll
            for (int s = 0; s < 4; ++s) {
                const float* p1 = wih1 + (size_t)row * H_ + s * 32 + grp * 8;
                const float* p2 = whh1 + (size_t)row * H_ + s * 32 + grp * 8;
                f16x8 f1, f2;
                #pragma unroll
                for (int jj = 0; jj < 8; ++jj) {
                    f1[jj] = (_Float16)p1[jj];
                    f2[jj] = (_Float16)p2[jj];
                }
                wih1f[j][s] = f1;
                whh1f[j][s] = f2;
            }
        }
        #pragma unroll
        for (int j = 0; j < 4; ++j)
            #pragma unroll
            for (int s = 0; s < 4; ++s) {
                asm("" : "+a"(wih1f[j][s]));
                asm("" : "+a"(whh1f[j][s]));
            }

        float bb1[4];
        #pragma unroll
        for (int j = 0; j < 4; ++j) {
            const int row = j * H_ + w * 16 + n;
            bb1[j] = bih1[row] + bhh1[row];
        }
        {
            float2 v = ((const float2*)wlin)[tid];
            wlin_p[(tid >> 6) * RING_LD + (tid & 63)] = pk2h(v.x, v.y);
        }
        if (tid < F_) blin_f[tid] = blin[tid];
        if (tid < 64) h1ring[63 * RING_LD + tid] = 0u;   // h1(-1) = 0
        __syncthreads();

        float c1 = 0.0f;
        const f32x4 Z4 = {0.0f, 0.0f, 0.0f, 0.0f};

        for (int c = 0; c < NCH; ++c) {
            while (__hip_atomic_load(&prog[b], __ATOMIC_ACQUIRE,
                                     __HIP_MEMORY_SCOPE_AGENT) < c + 1)
                __builtin_amdgcn_s_sleep(8);
            const unsigned* src = h0g + ((size_t)b * GRING + (c & (GRING - 1))) * H0_DW;
            {
                const int tick = tid >> 3;
                const int off  = (tid & 7) * 8;
                uint4 v0 = *(const uint4*)&src[tick * 64 + off];
                uint4 v1 = *(const uint4*)&src[tick * 64 + off + 4];
                *(uint4*)&h0c[tick * RING_LD + off]     = v0;
                *(uint4*)&h0c[tick * RING_LD + off + 4] = v1;
            }
            __syncthreads();   // staged (loads drained)
            if (tid == 0)
                __hip_atomic_store(&done[b], c + 1, __ATOMIC_RELAXED,
                                   __HIP_MEMORY_SCOPE_AGENT);

            for (int half = 0; half < 2; ++half) {
                // ---- batched GEMM: zih1 for 32 ticks ----
                #pragma unroll
                for (int mt = 0; mt < 2; ++mt) {
                    f32x4 d0 = Z4, d1 = Z4, d2 = Z4, d3 = Z4;
                    const int trow = half * 32 + mt * 16 + n;
                    #pragma unroll
                    for (int s = 0; s < 4; ++s) {
                        f16x8 ah = __builtin_bit_cast(
                            f16x8, *(const uint4*)&h0c[trow * RING_LD + s * 16 + grp * 4]);
                        d0 = mfma16(ah, wih1f[0][s], d0);
                        d1 = mfma16(ah, wih1f[1][s], d1);
                        d2 = mfma16(ah, wih1f[2][s], d2);
                        d3 = mfma16(ah, wih1f[3][s], d3);
                    }
                    const int zr = mt * 16 + grp * 4;
                    #pragma unroll
                    for (int reg = 0; reg < 4; ++reg) {
                        zih1[(zr + reg) * Z_LD + 0 * H_ + w * 16 + n] = d0[reg];
                        zih1[(zr + reg) * Z_LD + 1 * H_ + w * 16 + n] = d1[reg];
                        zih1[(zr + reg) * Z_LD + 2 * H_ + w * 16 + n] = d2[reg];
                        zih1[(zr + reg) * Z_LD + 3 * H_ + w * 16 + n] = d3[reg];
                    }
                }
                // no barrier: zih1 cols of wave w written and read only by wave w

                // ---- 32 serial ticks: 4-deep hh1 chain + zih1 scalar ----
                for (int tk = 0; tk < 32; ++tk) {
                    const int t  = c * CHUNK + half * 32 + tk;
                    const unsigned* h1r = &h1ring[((t + 63) & 63) * RING_LD];
                    f32x4 a0, a1, a2, a3;
                    {
                        f16x8 ah = __builtin_bit_cast(f16x8, *(const uint4*)&h1r[grp * 4]);
                        a0 = mfma16(ah, whh1f[0][0], Z4);
                        a1 = mfma16(ah, whh1f[1][0], Z4);
                        a2 = mfma16(ah, whh1f[2][0], Z4);
                        a3 = mfma16(ah, whh1f[3][0], Z4);
                    }
                    #pragma unroll
                    for (int s = 1; s < 4; ++s) {
                        f16x8 ah = __builtin_bit_cast(
                            f16x8, *(const uint4*)&h1r[s * 16 + grp * 4]);
                        a0 = mfma16(ah, whh1f[0][s], a0);
                        a1 = mfma16(ah, whh1f[1][s], a1);
                        a2 = mfma16(ah, whh1f[2][s], a2);
                        a3 = mfma16(ah, whh1f[3][s], a3);
                    }
                    const float* zp = &zih1[tk * Z_LD];
                    float gi = sigm(a0[0] + zp[0 * H_ + w * 16 + n] + bb1[0]);
                    float gf = sigm(a1[0] + zp[1 * H_ + w * 16 + n] + bb1[1]);
                    float gg = tanh_f(a2[0] + zp[2 * H_ + w * 16 + n] + bb1[2]);
                    float go = sigm(a3[0] + zp[3 * H_ + w * 16 + n] + bb1[3]);
                    c1 = gf * c1 + gi * gg;
                    float hh = go * tanh_f(c1);
                    if (l < 16)
                        ((_Float16*)&h1ring[(t & 63) * RING_LD])[w * 16 + l] = (_Float16)hh;
                    __syncthreads();   // h1(t) visible
                }
            }

            // ---- OUT burst for this chunk (r13-verified pattern) ----
            {
                const int tick_i = tid >> 3;
                const int fo     = tid & 7;
                const unsigned* hp = &h1ring[tick_i * RING_LD];
                const unsigned* wv = &wlin_p[fo * RING_LD];
                float a = 0.0f;
                #pragma unroll
                for (int j = 0; j < 16; ++j) {
                    uint4 hv = *(const uint4*)&hp[j * 4];
                    uint4 wq = *(const uint4*)&wv[j * 4];
                    a = fdot2a(wq.x, hv.x, a);
                    a = fdot2a(wq.y, hv.y, a);
                    a = fdot2a(wq.z, hv.z, a);
                    a = fdot2a(wq.w, hv.w, a);
                }
                out[(size_t)b * T_ * F_ + (size_t)c * CHUNK * F_ + tid] = a + blin_f[fo];
                // drains at next chunk's staging barrier
            }
        }
    }
}

// ===================== Fallback (round-5 verified, 3162 us) =====================
__global__ __launch_bounds__(512, 2)
void lstm2_burst_kernel(const float* __restrict__ x,
                        const float* __restrict__ wih0,
                        const float* __restrict__ whh0,
                        const float* __restrict__ bih0,
                        const float* __restrict__ bhh0,
                        const float* __restrict__ wih1,
                        const float* __restrict__ whh1,
                        const float* __restrict__ bih1,
                        const float* __restrict__ bhh1,
                        const float* __restrict__ wlin,
                        const float* __restrict__ blin,
                        float* __restrict__ out)
{
    __shared__ __align__(16) unsigned x_lds[T_ * F_ / 2];
    __shared__ __align__(16) unsigned h0_p[2][H_ / 2];
    __shared__ __align__(16) unsigned h1_ring[64 * RING_LD];
    __shared__ __align__(16) unsigned wlin_p[F_ * RING_LD];
    __shared__ float blin_f[F_];

    const int tid   = threadIdx.x;
    const int b     = blockIdx.x;
    const int h_idx = tid >> 2;
    const int sub   = tid & 3;
    const int grow  = (0x3120 >> (sub * 4)) & 0xF;
    const int row   = grow * H_ + h_idx;

    const float4* xp = (const float4*)(x + (size_t)b * T_ * F_);
    #pragma unroll
    for (int i = 0; i < 8; ++i) {
        int idx = tid + i * 512;
        float4 v = xp[idx];
        x_lds[idx * 2 + 0] = pk2h(v.x, v.y);
        x_lds[idx * 2 + 1] = pk2h(v.z, v.w);
    }

    unsigned rwih0[4];
    {
        const float4* p = (const float4*)(wih0 + (size_t)row * F_);
        float4 v0 = p[0], v1 = p[1];
        rwih0[0] = pk2h(v0.x, v0.y); rwih0[1] = pk2h(v0.z, v0.w);
        rwih0[2] = pk2h(v1.x, v1.y); rwih0[3] = pk2h(v1.z, v1.w);
    }
    unsigned rwhh0[64], rwih1[64], rwhh1[64];
    {
        const float4* p = (const float4*)(whh0 + (size_t)row * H_);
        #pragma unroll
        for (int i = 0; i < 32; ++i) {
            float4 v = p[i];
            rwhh0[i * 2 + 0] = pk2h(v.x, v.y);
            rwhh0[i * 2 + 1] = pk2h(v.z, v.w);
        }
    }
    {
        const float4* p = (const float4*)(wih1 + (size_t)row * H_);
        #pragma unroll
        for (int i = 0; i < 32; ++i) {
            float4 v = p[i];
            rwih1[i * 2 + 0] = pk2h(v.x, v.y);
            rwih1[i * 2 + 1] = pk2h(v.z, v.w);
        }
    }
    {
        const float4* p = (const float4*)(whh1 + (size_t)row * H_);
        #pragma unroll
        for (int i = 0; i < 32; ++i) {
            float4 v = p[i];
            rwhh1[i * 2 + 0] = pk2h(v.x, v.y);
            rwhh1[i * 2 + 1] = pk2h(v.z, v.w);
        }
    }
    const float bias0 = bih0[row] + bhh0[row];
    const float bias1 = bih1[row] + bhh1[row];

    {
        int r = tid >> 6, c = tid & 63;
        float2 v = ((const float2*)wlin)[r * 64 + c];
        wlin_p[r * RING_LD + c] = pk2h(v.x, v.y);
    }
    if (tid < F_) blin_f[tid] = blin[tid];
    if (tid < H_ / 2) { h0_p[0][tid] = 0u; h0_p[1][tid] = 0u; }
    if (tid < H_ / 2) h1_ring[63 * RING_LD + tid] = 0u;
    __syncthreads();

    const bool is_g = (sub == 1);
    const bool lo2  = (sub < 2);
    float c0 = 0.0f, c1 = 0.0f;

    for (int t = 0; t < T_; ++t) {
        const int rp = (t + 1) & 1;
        const int wp = t & 1;
        {
            float aa = bias0, ab = 0.0f;
            uint4 xv = *(const uint4*)&x_lds[t * 4];
            aa = fdot2a(rwih0[0], xv.x, aa);
            ab = fdot2a(rwih0[1], xv.y, ab);
            aa = fdot2a(rwih0[2], xv.z, aa);
            ab = fdot2a(rwih0[3], xv.w, ab);
            const unsigned* hr = &h0_p[rp][0];
            #pragma unroll
            for (int j = 0; j < 16; ++j) {
                uint4 hv = *(const uint4*)&hr[j * 4];
                aa = fdot2a(rwhh0[j * 4 + 0], hv.x, aa);
                ab = fdot2a(rwhh0[j * 4 + 1], hv.y, ab);
                aa = fdot2a(rwhh0[j * 4 + 2], hv.z, aa);
                ab = fdot2a(rwhh0[j * 4 + 3], hv.w, ab);
            }
            float a = aa + ab;
            float xin = is_g ? 2.0f * a : a;
            float s   = sigm(xin);
            float act = is_g ? 2.0f * s - 1.0f : s;
            float s1  = lane_xor1(act);
            float p   = lo2 ? act * s1 : (sub == 2 ? act : s1) * c0;
            float cn  = p + lane_xor2(p);
            c0 = cn;
            float oval = (sub == 2) ? s1 : act;
            float h = oval * tanh_f(cn);
            if (sub == 2) ((_Float16*)&h0_p[wp][0])[h_idx] = (_Float16)h;
        }
        __syncthreads();
        {
            float aa = bias1, ab = 0.0f, ba = 0.0f, bb = 0.0f;
            const unsigned* h0r = &h0_p[wp][0];
            const unsigned* h1r = &h1_ring[((t + 63) & 63) * RING_LD];
            #pragma unroll
            for (int j = 0; j < 16; ++j) {
                uint4 hv0 = *(const uint4*)&h0r[j * 4];
                uint4 hv1 = *(const uint4*)&h1r[j * 4];
                aa = fdot2a(rwih1[j * 4 + 0], hv0.x, aa);
                ab = fdot2a(rwih1[j * 4 + 1], hv0.y, ab);
                aa = fdot2a(rwih1[j * 4 + 2], hv0.z, aa);
                ab = fdot2a(rwih1[j * 4 + 3], hv0.w, ab);
                ba = fdot2a(rwhh1[j * 4 + 0], hv1.x, ba);
                bb = fdot2a(rwhh1[j * 4 + 1], hv1.y, bb);
                ba = fdot2a(rwhh1[j * 4 + 2], hv1.z, ba);
                bb = fdot2a(rwhh1[j * 4 + 3], hv1.w, bb);
            }
            float a = (aa + ab) + (ba + bb);
            float xin = is_g ? 2.0f * a : a;
            float s   = sigm(xin);
            float act = is_g ? 2.0f * s - 1.0f : s;
            float s1  = lane_xor1(act);
            float p   = lo2 ? act * s1 : (sub == 2 ? act : s1) * c1;
            float cn  = p + lane_xor2(p);
            c1 = cn;
            float oval = (sub == 2) ? s1 : act;
            float h = oval * tanh_f(cn);
            if (sub == 2)
                ((_Float16*)&h1_ring[(t & 63) * RING_LD])[h_idx] = (_Float16)h;
        }
        __syncthreads();
        if ((t & 63) == 63) {
            const int tick_i = tid >> 3;
            const int fo     = tid & 7;
            const unsigned* hp = &h1_ring[tick_i * RING_LD];
            const unsigned* wv = &wlin_p[fo * RING_LD];
            float a = 0.0f;
            #pragma unroll
            for (int j = 0; j < 16; ++j) {
                uint4 hv = *(const uint4*)&hp[j * 4];
                uint4 wq = *(const uint4*)&wv[j * 4];
                a = fdot2a(wq.x, hv.x, a);
                a = fdot2a(wq.y, hv.y, a);
                a = fdot2a(wq.z, hv.z, a);
                a = fdot2a(wq.w, hv.w, a);
            }
            out[(size_t)b * T_ * F_ + (size_t)(t - 63) * F_ + tid] = a + blin_f[fo];
        }
    }
}

extern "C" void kernel_launch(void* const* d_in, const int* in_sizes, int n_in,
                              void* d_out, int out_size, void* d_ws, size_t ws_size,
                              hipStream_t stream) {
    const float* x    = (const float*)d_in[0];
    const float* wih0 = (const float*)d_in[1];
    const float* whh0 = (const float*)d_in[2];
    const float* bih0 = (const float*)d_in[3];
    const float* bhh0 = (const float*)d_in[4];
    const float* wih1 = (const float*)d_in[5];
    const float* whh1 = (const float*)d_in[6];
    const float* bih1 = (const float*)d_in[7];
    const float* bhh1 = (const float*)d_in[8];
    const float* wlin = (const float*)d_in[9];
    const float* blin = (const float*)d_in[10];
    float* out = (float*)d_out;

    const size_t h0_bytes = (size_t)B_ * GRING * H0_DW * sizeof(unsigned);  // 16 MB
    const size_t need = h0_bytes + 512;
    if (d_ws != nullptr && ws_size >= need) {
        unsigned* h0g = (unsigned*)d_ws;
        int* flags = (int*)((char*)d_ws + h0_bytes);   // prog[64], done[64]
        hipMemsetAsync(flags, 0, 512, stream);
        lstm2_pc5_kernel<<<dim3(128), dim3(512), 0, stream>>>(
            x, wih0, whh0, bih0, bhh0, wih1, whh1, bih1, bhh1, wlin, blin,
            h0g, flags, out);
    } else {
        lstm2_burst_kernel<<<dim3(B_), dim3(512), 0, stream>>>(
            x, wih0, whh0, bih0, bhh0, wih1, whh1, bih1, bhh1, wlin, blin, out);
    }
}